// Round 11
// baseline (832.403 us; speedup 1.0000x reference)
//
#include <hip/hip_runtime.h>
#include <hip/hip_bf16.h>
#include <stdint.h>

// ---------------------------------------------------------------------------
// UVSeamGNN R9: XCC_ID-pinned edge kernel (bucket = s_getreg(HW_REG_XCC_ID),
// per-bucket atomic tile counters + cross-bucket stealing) over a
// (src-bucket, dst)-ordered edge list built directly in the CSR scatter
// (replaces R8's 3-kernel partition that cost +57us and didn't pin).
// dst-order CSR (rowptr/src4) kept for agg kernels.
// Workspace (4B words), N=100000, E=1600000:
//   rowptr  @0        [100001]
//   cursor  @100004   [100000]   -- zero region start
//   cur_bd  @200004   [800000]
//   tilecnt @1000004  [128]      -- zero region end (900128 words)
//   partial @1000132  [4096]
//   bB      @1004228  [12]
//   src4    @1004240  [E]
//   rec2    @2604240  [E*4]    (uint4: src|dstlo<<17, dsthi|eid<<2, attr01, attr23)
//   mean1   @9004240  [N*6]
//   cat2b   @9604240  [N*256]b
//   h2b     @22404240 [N*128]b
//   B2f     @28804240 [16384w]  WSDf @28820624 [16384w]
//   W2f     @28837008 [4096w]   pbias@28841104 [256w]
// total ~115.4 MB
// ---------------------------------------------------------------------------

typedef unsigned short u16;
typedef short bf16x8 __attribute__((ext_vector_type(8)));
typedef float f32x4 __attribute__((ext_vector_type(4)));
typedef float f32x2 __attribute__((ext_vector_type(2)));

#define NMASK 0x1FFFF

__device__ __forceinline__ u16 f2b(float f) {
  unsigned u = __builtin_bit_cast(unsigned, f);
  u = u + 0x7fffu + ((u >> 16) & 1u);
  return (u16)(u >> 16);
}
__device__ __forceinline__ float bflo(unsigned u) {
  return __builtin_bit_cast(float, u << 16);
}
__device__ __forceinline__ float bfhi(unsigned u) {
  return __builtin_bit_cast(float, u & 0xffff0000u);
}
__device__ __forceinline__ f32x2 unpk2(unsigned u) {
  return (f32x2){bflo(u), bfhi(u)};
}
__device__ __forceinline__ unsigned pack2bf(float a, float b) {
  unsigned ua = __builtin_bit_cast(unsigned, a);
  unsigned ub = __builtin_bit_cast(unsigned, b);
  ua = ua + 0x7fffu + ((ua >> 16) & 1u);
  ub = ub + 0x7fffu + ((ub >> 16) & 1u);
  return (ua >> 16) | (ub & 0xffff0000u);
}
__device__ __forceinline__ unsigned packrn(f32x2 f) {
  __hip_bfloat162 h = __float22bfloat162_rn(make_float2(f.x, f.y));
  unsigned r;
  __builtin_memcpy(&r, &h, 4);
  return r;
}

// ---- histograms: dst (for agg CSR) and (bucket,dst) (for edge CSR) ----
__global__ void hist_both(const int* __restrict__ ei, int* __restrict__ cnt_d,
                          int* __restrict__ cnt_bd, int E, int N, int bdiv) {
  int e = blockIdx.x * blockDim.x + threadIdx.x;
  if (e >= E) return;
  int s = ei[e];
  int d = ei[E + e];
  atomicAdd(&cnt_d[d], 1);
  atomicAdd(&cnt_bd[(size_t)(s / bdiv) * N + d], 1);
}

__global__ void scan_block_sums(const int* __restrict__ cnt,
                                int* __restrict__ partial, int M) {
  __shared__ int red[256];
  int t = threadIdx.x;
  int n = blockIdx.x * 256 + t;
  red[t] = (n < M) ? cnt[n] : 0;
  __syncthreads();
  for (int off = 128; off; off >>= 1) {
    if (t < off) red[t] += red[t + off];
    __syncthreads();
  }
  if (t == 0) partial[blockIdx.x] = red[0];
}

// chunked exclusive scan of partial[0..NBLK), single block of 256
__global__ void scan_mid(int* __restrict__ partial, int* __restrict__ bB,
                         int NBLK, int E, int setBB) {
  __shared__ int ls[256];
  int t = threadIdx.x;
  int chunk = (NBLK + 255) >> 8;
  int s = 0;
  for (int j = 0; j < chunk; j++) {
    int i = t * chunk + j;
    if (i < NBLK) s += partial[i];
  }
  ls[t] = s;
  __syncthreads();
  for (int off = 1; off < 256; off <<= 1) {
    int a = (t >= off) ? ls[t - off] : 0;
    __syncthreads();
    ls[t] += a;
    __syncthreads();
  }
  int run = ls[t] - s;
  for (int j = 0; j < chunk; j++) {
    int i = t * chunk + j;
    if (i < NBLK) {
      int v = partial[i];
      partial[i] = run;
      run += v;
    }
  }
  if (setBB && t == 0) bB[8] = E;
}

// finalize dst CSR: rowptr + cursor = exclusive offsets
__global__ void scan_final(const int* __restrict__ partial,
                           int* __restrict__ cursor, int* __restrict__ rowptr,
                           int N, int E) {
  __shared__ int sc[256];
  int t = threadIdx.x;
  int n = blockIdx.x * 256 + t;
  int v = (n < N) ? cursor[n] : 0;
  sc[t] = v;
  __syncthreads();
  for (int off = 1; off < 256; off <<= 1) {
    int a = (t >= off) ? sc[t - off] : 0;
    __syncthreads();
    sc[t] += a;
    __syncthreads();
  }
  int excl = partial[blockIdx.x] + sc[t] - v;
  if (n < N) {
    rowptr[n] = excl;
    cursor[n] = excl;
  }
  if (n == 0) rowptr[N] = E;
}

// finalize (bucket,dst) CSR: cur_bd = exclusive offsets, bB boundaries
__global__ void scan_final_bd(const int* __restrict__ partial,
                              int* __restrict__ cur, int* __restrict__ bB,
                              int M, int N) {
  __shared__ int sc[256];
  int t = threadIdx.x;
  int n = blockIdx.x * 256 + t;
  int v = (n < M) ? cur[n] : 0;
  sc[t] = v;
  __syncthreads();
  for (int off = 1; off < 256; off <<= 1) {
    int a = (t >= off) ? sc[t - off] : 0;
    __syncthreads();
    sc[t] += a;
    __syncthreads();
  }
  int excl = partial[blockIdx.x] + sc[t] - v;
  if (n < M) {
    cur[n] = excl;
    if (n - (n / N) * N == 0) bB[n / N] = excl;
  }
}

// scatter: src4 in dst-order (agg CSR), rec2 in (bucket,dst)-order (edge CSR)
__global__ void scatter_both(const int* __restrict__ ei,
                             const float* __restrict__ attr,
                             int* __restrict__ cursor, int* __restrict__ cur_bd,
                             unsigned* __restrict__ src4,
                             uint4* __restrict__ rec2, int E, int N, int bdiv) {
  int e = blockIdx.x * blockDim.x + threadIdx.x;
  if (e >= E) return;
  int s = ei[e];
  int d = ei[E + e];
  float4 a4 = *(const float4*)(attr + (size_t)e * 4);
  int p1 = atomicAdd(&cursor[d], 1);
  src4[p1] = (unsigned)s;
  int p2 = atomicAdd(&cur_bd[(size_t)(s / bdiv) * N + d], 1);
  uint4 r;
  r.x = (unsigned)s | ((unsigned)(d & 0x7FFF) << 17);
  r.y = ((unsigned)d >> 15) | ((unsigned)e << 2);
  r.z = pack2bf(a4.x, a4.y);
  r.w = pack2bf(a4.z, a4.w);
  rec2[p2] = r;
}

// ---- pack weights into bf16 MFMA B-fragment layouts ----
__global__ void pack_weights(const float* __restrict__ w2_root,
                             const float* __restrict__ w2_neigh,
                             const float* __restrict__ w_e1,
                             const float* __restrict__ w_e2,
                             const float* __restrict__ b_e1,
                             u16* __restrict__ B2f, u16* __restrict__ WSDf,
                             u16* __restrict__ W2f, float* __restrict__ pbias) {
  int t = blockIdx.x * 256 + threadIdx.x;
  if (t < 32768) {  // B2f: KT=8, NT=8 over [w2_root; w2_neigh] (K=256, N=128)
    int j = t & 7, lane = (t >> 3) & 63, nt = (t >> 9) & 7, kt = t >> 12;
    int k = kt * 32 + (lane >> 4) * 8 + j;
    int n = nt * 16 + (lane & 15);
    float v = (k < 128) ? w2_root[k * 128 + n] : w2_neigh[(k - 128) * 128 + n];
    B2f[t] = f2b(v);
  } else if (t < 65536) {  // WSDf: KT=4, NT=16 over [Ws | Wd] (K=128, N=256)
    int t2 = t - 32768;
    int j = t2 & 7, lane = (t2 >> 3) & 63, nt = (t2 >> 9) & 15, kt = t2 >> 13;
    int k = kt * 32 + (lane >> 4) * 8 + j;
    int n = nt * 16 + (lane & 15);
    float v = (n < 128) ? w_e1[k * 128 + n] : w_e1[(128 + k) * 128 + (n - 128)];
    WSDf[t2] = f2b(v);
  } else if (t < 73728) {  // W2f: KT=4, NT=4 over w_e2 (K=128, N=64)
    int t2 = t - 65536;
    int j = t2 & 7, lane = (t2 >> 3) & 63, nt = (t2 >> 9) & 3, kt = t2 >> 11;
    int k = kt * 32 + (lane >> 4) * 8 + j;
    int n = nt * 16 + (lane & 15);
    W2f[t2] = f2b(w_e2[k * 64 + n]);
  } else if (t < 73984) {  // pbias
    int n = t - 73728;
    pbias[n] = (n < 128) ? 0.0f : b_e1[n - 128];
  }
}

// ---- layer-1 mean aggregation: wave/node, 8 rows x 8 lanes, 4-deep ----
__global__ __launch_bounds__(256) void agg1_kernel(
    const float* __restrict__ x, const int* __restrict__ rowptr,
    const unsigned* __restrict__ src4, float* __restrict__ mean1, int N) {
  int n = blockIdx.x * 4 + (threadIdx.x >> 6);
  if (n >= N) return;
  int lane = threadIdx.x & 63;
  int g = lane >> 3;
  int c = lane & 7;
  int beg = rowptr[n], end = rowptr[n + 1];
  float a = 0.0f;
  if (c < 6) {
    int idx[4];
#pragma unroll
    for (int j = 0; j < 4; j++) {
      int ii = beg + g + j * 8;
      idx[j] = (ii < end) ? (int)src4[ii] : -1;
    }
    float v[4];
#pragma unroll
    for (int j = 0; j < 4; j++)
      v[j] = x[(size_t)(idx[j] < 0 ? 0 : idx[j]) * 6 + c];
#pragma unroll
    for (int j = 0; j < 4; j++)
      if (idx[j] >= 0) a += v[j];
    for (int ii = beg + g + 32; ii < end; ii += 8) {
      a += x[(size_t)src4[ii] * 6 + c];
    }
  }
  a += __shfl_xor(a, 8, 64);
  a += __shfl_xor(a, 16, 64);
  a += __shfl_xor(a, 32, 64);
  if (g == 0 && c < 6)
    mean1[(size_t)n * 6 + c] = a / (float)max(end - beg, 1);
}

// ---- dense layer 1 -> h1 bf16 into cat2b cols 0..127, LDS-staged ----
__global__ __launch_bounds__(256) void dense1_kernel(
    const float* __restrict__ x, const float* __restrict__ mean1,
    const float* __restrict__ w_root, const float* __restrict__ w_neigh,
    const float* __restrict__ b, u16* __restrict__ cat2b, int N) {
  __shared__ float sxm[384];
  int t = threadIdx.x;
  int col = t & 127;
  int half = t >> 7;
  float wr[6], wn[6];
#pragma unroll
  for (int j = 0; j < 6; j++) {
    wr[j] = w_root[j * 128 + col];
    wn[j] = w_neigh[j * 128 + col];
  }
  float bb = b[col];
  for (int base = blockIdx.x * 32; base < N; base += gridDim.x * 32) {
    int cnt = min(32, N - base) * 6;
    __syncthreads();
    for (int i = t; i < 384; i += 256) {
      if (i < 192)
        sxm[i] = (i < cnt) ? x[(size_t)base * 6 + i] : 0.0f;
      else
        sxm[i] = (i - 192 < cnt) ? mean1[(size_t)base * 6 + (i - 192)] : 0.0f;
    }
    __syncthreads();
#pragma unroll
    for (int sub = 0; sub < 16; sub++) {
      int nl = sub * 2 + half;
      int n = base + nl;
      if (n < N) {
        float s = bb;
#pragma unroll
        for (int j = 0; j < 6; j++)
          s += sxm[nl * 6 + j] * wr[j] + sxm[192 + nl * 6 + j] * wn[j];
        cat2b[(size_t)n * 256 + col] = f2b(fmaxf(s, 0.0f));
      }
    }
  }
}

// ---- layer-2 mean aggregation: wave/node, 4x16 lanes, 8-deep prefetch ----
__global__ __launch_bounds__(256) void agg2_kernel(
    const u16* __restrict__ cat2b, u16* __restrict__ cat2w,
    const int* __restrict__ rowptr, const unsigned* __restrict__ src4, int N) {
  int n = blockIdx.x * 4 + (threadIdx.x >> 6);
  if (n >= N) return;
  int lane = threadIdx.x & 63;
  int g = lane >> 4;
  int c = lane & 15;
  int beg = rowptr[n], end = rowptr[n + 1];
  f32x2 acc2[4];
#pragma unroll
  for (int j = 0; j < 4; j++) acc2[j] = (f32x2){0.f, 0.f};

  const int DEPTH = 8;
  int idx[DEPTH];
#pragma unroll
  for (int j = 0; j < DEPTH; j++) {
    int ii = beg + g + j * 4;
    idx[j] = (ii < end) ? (int)src4[ii] : -1;
  }
  uint4 u[DEPTH];
#pragma unroll
  for (int j = 0; j < DEPTH; j++) {
    int s = idx[j] < 0 ? 0 : idx[j];
    u[j] = *(const uint4*)(cat2b + (size_t)s * 256 + c * 8);
  }
#pragma unroll
  for (int j = 0; j < DEPTH; j++) {
    if (idx[j] >= 0) {
      acc2[0] += unpk2(u[j].x);
      acc2[1] += unpk2(u[j].y);
      acc2[2] += unpk2(u[j].z);
      acc2[3] += unpk2(u[j].w);
    }
  }
  for (int ii = beg + g + DEPTH * 4; ii < end; ii += 4) {
    uint4 uu = *(const uint4*)(cat2b + (size_t)src4[ii] * 256 + c * 8);
    acc2[0] += unpk2(uu.x);
    acc2[1] += unpk2(uu.y);
    acc2[2] += unpk2(uu.z);
    acc2[3] += unpk2(uu.w);
  }
#pragma unroll
  for (int j = 0; j < 4; j++) {
    acc2[j].x += __shfl_xor(acc2[j].x, 16, 64);
    acc2[j].y += __shfl_xor(acc2[j].y, 16, 64);
    acc2[j].x += __shfl_xor(acc2[j].x, 32, 64);
    acc2[j].y += __shfl_xor(acc2[j].y, 32, 64);
  }
  if (g == 0) {
    float inv = 1.0f / (float)max(end - beg, 1);
    uint4 ov;
    ov.x = packrn(acc2[0] * inv);
    ov.y = packrn(acc2[1] * inv);
    ov.z = packrn(acc2[2] * inv);
    ov.w = packrn(acc2[3] * inv);
    *(uint4*)(cat2w + (size_t)n * 256 + 128 + c * 8) = ov;
  }
}

// ---- bf16 MFMA GEMM: 512 thr, 8 waves, M-tile 128 ----
template <int KT, int NT, bool RELU>
__global__ __launch_bounds__(512) void mfma_gemm(
    const u16* __restrict__ A, int lda, const u16* __restrict__ Bf,
    const float* __restrict__ bias, u16* __restrict__ C, int ldc, int M) {
  __shared__ u16 sB[KT * NT * 512];
  int tid = threadIdx.x;
  for (int i = tid; i < KT * NT * 64; i += 512)
    ((uint4*)sB)[i] = ((const uint4*)Bf)[i];
  int w = tid >> 6, l = tid & 63;
  int quad = l >> 4, col16 = l & 15;
  int rowA = blockIdx.x * 128 + w * 16 + col16;
  bool rv = rowA < M;
  const u16* ap = A + (size_t)rowA * lda + quad * 8;
  f32x4 acc[NT];
#pragma unroll
  for (int nt = 0; nt < NT; nt++) acc[nt] = (f32x4){0.f, 0.f, 0.f, 0.f};
  __syncthreads();
#pragma unroll
  for (int kt = 0; kt < KT; kt++) {
    bf16x8 av = {};
    if (rv) av = *(const bf16x8*)(ap + kt * 32);
#pragma unroll
    for (int nt = 0; nt < NT; nt++) {
      bf16x8 bv = *(const bf16x8*)(sB + ((kt * NT + nt) * 64 + l) * 8);
      acc[nt] = __builtin_amdgcn_mfma_f32_16x16x32_bf16(av, bv, acc[nt], 0, 0, 0);
    }
  }
  int rowbase = blockIdx.x * 128 + w * 16 + quad * 4;
#pragma unroll
  for (int r = 0; r < 4; r++) {
    int row = rowbase + r;
    if (row < M) {
#pragma unroll
      for (int nt = 0; nt < NT; nt++) {
        float v = acc[nt][r] + bias[nt * 16 + col16];
        if (RELU) v = fmaxf(v, 0.0f);
        C[(size_t)row * ldc + nt * 16 + col16] = f2b(v);
      }
    }
  }
}

// ---- XCC-pinned pipelined edge MLP ----
__global__ __launch_bounds__(256) void edge_mfma_kernel(
    const u16* __restrict__ Pcatb, const uint4* __restrict__ rec2,
    const int* __restrict__ bB, int* __restrict__ tilecnt,
    const u16* __restrict__ W2f, const float* __restrict__ b_e2,
    const float* __restrict__ w_e3, const float* __restrict__ b_e3,
    const float* __restrict__ w_e1, float* __restrict__ out) {
  __shared__ u16 sV[64 * 136];  // cols 0..127 = V, u16 slot 128.. = eid
  __shared__ u16 sW2[8192];
  __shared__ int sTile;

  int tid = threadIdx.x;
  int w = tid >> 6, l = tid & 63, quad = l >> 4, c16 = l & 15;
  int egrp = tid >> 4, ac16 = tid & 15;

  for (int i = tid; i < 1024; i += 256)
    ((uint4*)sW2)[i] = ((const uint4*)W2f)[i];

  f32x2 wa2[4][4];
#pragma unroll
  for (int j = 0; j < 4; j++) {
    float4 w0 = *(const float4*)(w_e1 + (256 + j) * 128 + ac16 * 8);
    float4 w1 = *(const float4*)(w_e1 + (256 + j) * 128 + ac16 * 8 + 4);
    wa2[j][0] = (f32x2){w0.x, w0.y};
    wa2[j][1] = (f32x2){w0.z, w0.w};
    wa2[j][2] = (f32x2){w1.x, w1.y};
    wa2[j][3] = (f32x2){w1.z, w1.w};
  }
  float w3v[4], be2[4];
#pragma unroll
  for (int nt = 0; nt < 4; nt++) {
    w3v[nt] = w_e3[nt * 16 + c16];
    be2[nt] = b_e2[nt * 16 + c16];
  }
  float b3 = b_e3[0];

  unsigned xcc;
  asm volatile("s_getreg_b32 %0, hwreg(HW_REG_XCC_ID)" : "=s"(xcc));

  uint4 rc[4], rcn[4];
  uint4 ps[4], pd[4];
  int eidr[4];

  // own bucket first (L2-resident Ps slice), then steal from others
  for (int bb = 0; bb < 8; bb++) {
    int bucket = (int)((xcc + (unsigned)bb) & 7u);
    int bBeg = bB[bucket], bEnd = bB[bucket + 1];
    int tiles = (bEnd - bBeg + 63) >> 6;
    int* tc = &tilecnt[bucket * 16];

    auto load_rc = [&](int t, uint4* dst) {
#pragma unroll
      for (int it = 0; it < 4; it++) {
        int e = min(bBeg + t * 64 + it * 16 + egrp, bEnd - 1);
        dst[it] = rec2[e];
      }
    };
    auto issue_gather = [&]() {
#pragma unroll
      for (int it = 0; it < 4; it++) {
        int s = (int)(rc[it].x & NMASK);
        int d = (int)(((rc[it].x >> 17) | (rc[it].y << 15)) & NMASK);
        eidr[it] = (int)(rc[it].y >> 2);
        ps[it] = *(const uint4*)(Pcatb + (size_t)s * 256 + ac16 * 8);
        pd[it] = *(const uint4*)(Pcatb + (size_t)d * 256 + 128 + ac16 * 8);
      }
    };

    __syncthreads();  // protect sTile across buckets
    if (tid == 0) sTile = atomicAdd(tc, 1);
    __syncthreads();
    int tcur = sTile;
    __syncthreads();
    if (tid == 0) sTile = atomicAdd(tc, 1);
    __syncthreads();
    int tnext = sTile;
    if (tcur >= tiles) continue;

    load_rc(tcur, rc);
    issue_gather();
    if (tnext < tiles) load_rc(tnext, rcn);

    while (tcur < tiles) {
      // ---- phase A (packed fp32): V = relu(Ps + Pd' + attr@Wa)
#pragma unroll
      for (int it = 0; it < 4; it++) {
        int e = it * 16 + egrp;
        uint4 psu = ps[it], pdu = pd[it];
        f32x2 a01 = unpk2(rc[it].z);
        f32x2 a23 = unpk2(rc[it].w);
        unsigned pu[4] = {psu.x, psu.y, psu.z, psu.w};
        unsigned du[4] = {pdu.x, pdu.y, pdu.z, pdu.w};
        uint4 ov;
        unsigned* op = (unsigned*)&ov;
#pragma unroll
        for (int p2 = 0; p2 < 4; p2++) {
          f32x2 f = unpk2(pu[p2]) + unpk2(du[p2]);
          f += a01.x * wa2[0][p2];
          f += a01.y * wa2[1][p2];
          f += a23.x * wa2[2][p2];
          f += a23.y * wa2[3][p2];
          f = __builtin_elementwise_max(f, (f32x2){0.f, 0.f});
          op[p2] = packrn(f);
        }
        *(uint4*)(sV + e * 136 + ac16 * 8) = ov;
        if (ac16 == 0) *(unsigned*)(sV + e * 136 + 128) = (unsigned)eidr[it];
      }
      // ---- rotate prefetch + grab next tile
      bool have_next = (tnext < tiles);
      if (have_next) {
#pragma unroll
        for (int it = 0; it < 4; it++) rc[it] = rcn[it];
        issue_gather();
      }
      if (tid == 0) sTile = atomicAdd(tc, 1);
      __syncthreads();  // sV + sTile visible
      int tnn = sTile;
      if (have_next && tnn < tiles) load_rc(tnn, rcn);
      // ---- phase B: MFMA from LDS
      f32x4 acc[4];
#pragma unroll
      for (int nt = 0; nt < 4; nt++) acc[nt] = (f32x4){0.f, 0.f, 0.f, 0.f};
      const u16* vp = sV + (w * 16 + c16) * 136 + quad * 8;
#pragma unroll
      for (int kt = 0; kt < 4; kt++) {
        bf16x8 av = *(const bf16x8*)(vp + kt * 32);
#pragma unroll
        for (int nt = 0; nt < 4; nt++) {
          bf16x8 bv = *(const bf16x8*)(sW2 + ((kt * 4 + nt) * 64 + l) * 8);
          acc[nt] =
              __builtin_amdgcn_mfma_f32_16x16x32_bf16(av, bv, acc[nt], 0, 0, 0);
        }
      }
#pragma unroll
      for (int r = 0; r < 4; r++) {
        float p = 0.0f;
#pragma unroll
        for (int nt = 0; nt < 4; nt++)
          p += fmaxf(acc[nt][r] + be2[nt], 0.0f) * w3v[nt];
        p += __shfl_xor(p, 1, 64);
        p += __shfl_xor(p, 2, 64);
        p += __shfl_xor(p, 4, 64);
        p += __shfl_xor(p, 8, 64);
        if (c16 == 0) {
          int eloc = w * 16 + quad * 4 + r;
          if (bBeg + tcur * 64 + eloc < bEnd) {
            unsigned eid = *(const unsigned*)(sV + eloc * 136 + 128);
            out[eid] = p + b3;
          }
        }
      }
      __syncthreads();  // protect sV/sTile before next iteration
      tcur = tnext;
      tnext = tnn;
    }
  }
}

extern "C" void kernel_launch(void* const* d_in, const int* in_sizes, int n_in,
                              void* d_out, int out_size, void* d_ws,
                              size_t ws_size, hipStream_t stream) {
  const float* x        = (const float*)d_in[0];
  const int*   ei       = (const int*)d_in[1];
  const float* attr     = (const float*)d_in[2];
  const float* w1_root  = (const float*)d_in[3];
  const float* w1_neigh = (const float*)d_in[4];
  const float* b1       = (const float*)d_in[5];
  const float* w2_root  = (const float*)d_in[6];
  const float* w2_neigh = (const float*)d_in[7];
  const float* b2       = (const float*)d_in[8];
  const float* w_e1     = (const float*)d_in[9];
  const float* b_e1     = (const float*)d_in[10];
  const float* w_e2     = (const float*)d_in[11];
  const float* b_e2     = (const float*)d_in[12];
  const float* w_e3     = (const float*)d_in[13];
  const float* b_e3     = (const float*)d_in[14];
  float* out = (float*)d_out;

  int N = in_sizes[0] / 6;
  int E = in_sizes[2] / 4;
  int NBLK = (N + 255) / 256;        // 391
  int M2 = 8 * N;                    // (bucket,dst) cells
  int NBLK2 = (M2 + 255) / 256;      // 3125
  int bdiv = (N + 7) / 8;

  int* wsi = (int*)d_ws;
  int*      rowptr  = wsi;                         // [N+1]
  int*      cursor  = wsi + 100004;                // [N]
  int*      cur_bd  = wsi + 200004;                // [8N]
  int*      tilecnt = wsi + 1000004;               // [128]
  int*      partial = wsi + 1000132;               // [4096]
  int*      bB      = wsi + 1004228;               // [12]
  unsigned* src4    = (unsigned*)(wsi + 1004240);  // [E]
  uint4*    rec2    = (uint4*)(wsi + 2604240);     // [E] x 16B
  float*    mean1   = (float*)(wsi + 9004240);     // [N,6]
  u16*      cat2b   = (u16*)(wsi + 9604240);       // [N,256] bf16
  u16*      h2b     = (u16*)(wsi + 22404240);      // [N,128] bf16
  u16*      B2f     = (u16*)(wsi + 28804240);      // 32768 u16
  u16*      WSDf    = (u16*)(wsi + 28820624);      // 32768 u16
  u16*      W2f     = (u16*)(wsi + 28837008);      // 8192 u16
  float*    pbias   = (float*)(wsi + 28841104);    // 256 f32

  // zero cursor + cur_bd + tilecnt in one shot
  (void)hipMemsetAsync(cursor, 0, (size_t)900128 * sizeof(int), stream);

  pack_weights<<<289, 256, 0, stream>>>(w2_root, w2_neigh, w_e1, w_e2, b_e1,
                                        B2f, WSDf, W2f, pbias);

  // dual CSR build: dst-order (aggs) + (src-bucket,dst)-order (edge kernel)
  hist_both<<<(E + 255) / 256, 256, 0, stream>>>(ei, cursor, cur_bd, E, N,
                                                 bdiv);
  scan_block_sums<<<NBLK, 256, 0, stream>>>(cursor, partial, N);
  scan_mid<<<1, 256, 0, stream>>>(partial, bB, NBLK, E, 0);
  scan_final<<<NBLK, 256, 0, stream>>>(partial, cursor, rowptr, N, E);
  scan_block_sums<<<NBLK2, 256, 0, stream>>>(cur_bd, partial, M2);
  scan_mid<<<1, 256, 0, stream>>>(partial, bB, NBLK2, E, 1);
  scan_final_bd<<<NBLK2, 256, 0, stream>>>(partial, cur_bd, bB, M2, N);
  scatter_both<<<(E + 255) / 256, 256, 0, stream>>>(ei, attr, cursor, cur_bd,
                                                    src4, rec2, E, N, bdiv);

  // layer 1
  agg1_kernel<<<(N + 3) / 4, 256, 0, stream>>>(x, rowptr, src4, mean1, N);
  dense1_kernel<<<1024, 256, 0, stream>>>(x, mean1, w1_root, w1_neigh, b1,
                                          cat2b, N);

  // layer 2 aggregation
  agg2_kernel<<<(N + 3) / 4, 256, 0, stream>>>(cat2b, cat2b, rowptr, src4, N);

  int gblocks = (N + 127) / 128;
  // h2 = relu([h1|mean2] @ [w2_root;w2_neigh] + b2)
  mfma_gemm<8, 8, true><<<gblocks, 512, 0, stream>>>(cat2b, 256, B2f, b2, h2b,
                                                     128, N);
  // Pcat = h2 @ [Ws|Wd] + [0|b_e1]
  mfma_gemm<4, 16, false><<<gblocks, 512, 0, stream>>>(h2b, 128, WSDf, pbias,
                                                       cat2b, 256, N);

  // XCC-pinned fused edge MLP
  edge_mfma_kernel<<<1024, 256, 0, stream>>>(cat2b, rec2, bB, tilecnt, W2f,
                                             b_e2, w_e3, b_e3, w_e1, out);
}

// Round 12
// 602.456 us; speedup vs baseline: 1.3817x; 1.3817x over previous
//
#include <hip/hip_runtime.h>
#include <hip/hip_bf16.h>
#include <stdint.h>

// ---------------------------------------------------------------------------
// UVSeamGNN R10: R7b structure (596us best) + ILP-batched CSR build.
// R9 exposed scatter kernels as latency-bound (VALUBusy 0.9%, occ 79%,
// one dependent atomic->write chain per thread). Now 4 edges/thread:
// int4 src/dst loads, 4 independent atomics in flight, batched writes.
// Workspace (4B words), N=100000, E=1600000:
//   rowptr @0        [N+1]
//   cursor @100004   [N]
//   partial@200004   [512]
//   src4   @200516   [E]
//   rec    @1800520  [E*4]   (uint4: src|dstlo<<17, dsthi|eid<<2, attr01, attr23)
//   mean1  @8200520  [N*6]
//   cat2b  @8800520  [N*256]b (cols 0..127: h1/Ps; 128..255: mean2/Pd+b1)
//   h2b    @21600520 [N*128]b (6.4M words -> ends 28000520)
//   B2f    @28000520 [16384w]  WSDf @28016904 [16384w]
//   W2f    @28033288 [4096w]   pbias@28037384 [256w]
// total ~112.2 MB
// ---------------------------------------------------------------------------

typedef unsigned short u16;
typedef short bf16x8 __attribute__((ext_vector_type(8)));
typedef float f32x4 __attribute__((ext_vector_type(4)));
typedef float f32x2 __attribute__((ext_vector_type(2)));

#define NMASK 0x1FFFF

__device__ __forceinline__ u16 f2b(float f) {
  unsigned u = __builtin_bit_cast(unsigned, f);
  u = u + 0x7fffu + ((u >> 16) & 1u);
  return (u16)(u >> 16);
}
__device__ __forceinline__ float bflo(unsigned u) {
  return __builtin_bit_cast(float, u << 16);
}
__device__ __forceinline__ float bfhi(unsigned u) {
  return __builtin_bit_cast(float, u & 0xffff0000u);
}
__device__ __forceinline__ f32x2 unpk2(unsigned u) {
  return (f32x2){bflo(u), bfhi(u)};
}
__device__ __forceinline__ unsigned pack2bf(float a, float b) {
  unsigned ua = __builtin_bit_cast(unsigned, a);
  unsigned ub = __builtin_bit_cast(unsigned, b);
  ua = ua + 0x7fffu + ((ua >> 16) & 1u);
  ub = ub + 0x7fffu + ((ub >> 16) & 1u);
  return (ua >> 16) | (ub & 0xffff0000u);
}
__device__ __forceinline__ unsigned packrn(f32x2 f) {
  __hip_bfloat162 h = __float22bfloat162_rn(make_float2(f.x, f.y));
  unsigned r;
  __builtin_memcpy(&r, &h, 4);
  return r;
}

// ---- CSR build (4 edges/thread for memory-level parallelism) ----
__global__ void hist_kernel(const int* __restrict__ ei, int* __restrict__ cnt,
                            int E) {
  int base = (blockIdx.x * blockDim.x + threadIdx.x) * 4;
  if (base >= E) return;
  if (base + 3 < E) {
    int4 d4 = *(const int4*)(ei + E + base);
    atomicAdd(&cnt[d4.x], 1);
    atomicAdd(&cnt[d4.y], 1);
    atomicAdd(&cnt[d4.z], 1);
    atomicAdd(&cnt[d4.w], 1);
  } else {
    for (int e = base; e < E; e++) atomicAdd(&cnt[ei[E + e]], 1);
  }
}

__global__ void scan_block_sums(const int* __restrict__ cnt,
                                int* __restrict__ partial, int N) {
  __shared__ int red[256];
  int t = threadIdx.x;
  int n = blockIdx.x * 256 + t;
  red[t] = (n < N) ? cnt[n] : 0;
  __syncthreads();
  for (int off = 128; off; off >>= 1) {
    if (t < off) red[t] += red[t + off];
    __syncthreads();
  }
  if (t == 0) partial[blockIdx.x] = red[0];
}

__global__ void scan_partials(int* __restrict__ partial,
                              int* __restrict__ rowptr, int NBLK, int E,
                              int N) {
  __shared__ int sc[512];
  int t = threadIdx.x;
  int v = (t < NBLK) ? partial[t] : 0;
  sc[t] = v;
  __syncthreads();
  for (int off = 1; off < 512; off <<= 1) {
    int a = (t >= off) ? sc[t - off] : 0;
    __syncthreads();
    sc[t] += a;
    __syncthreads();
  }
  if (t < NBLK) partial[t] = sc[t] - v;  // exclusive
  if (t == 0) rowptr[N] = E;
}

__global__ void scan_final(const int* __restrict__ partial,
                           int* __restrict__ cursor, int* __restrict__ rowptr,
                           int N) {
  __shared__ int sc[256];
  int t = threadIdx.x;
  int n = blockIdx.x * 256 + t;
  int v = (n < N) ? cursor[n] : 0;
  sc[t] = v;
  __syncthreads();
  for (int off = 1; off < 256; off <<= 1) {
    int a = (t >= off) ? sc[t - off] : 0;
    __syncthreads();
    sc[t] += a;
    __syncthreads();
  }
  int excl = partial[blockIdx.x] + sc[t] - v;
  if (n < N) {
    rowptr[n] = excl;
    cursor[n] = excl;
  }
}

// scatter packed 16B record + src-only array, 4 edges/thread (ILP)
__global__ void scatter_rec(const int* __restrict__ ei,
                            const float* __restrict__ attr,
                            int* __restrict__ cursor, uint4* __restrict__ rec,
                            unsigned* __restrict__ src4, int E) {
  int base = (blockIdx.x * blockDim.x + threadIdx.x) * 4;
  if (base >= E) return;
  if (base + 3 < E) {
    int4 s4 = *(const int4*)(ei + base);
    int4 d4 = *(const int4*)(ei + E + base);
    const float4* ap = (const float4*)attr;
    float4 a0 = ap[base], a1 = ap[base + 1], a2 = ap[base + 2],
           a3 = ap[base + 3];
    int ss[4] = {s4.x, s4.y, s4.z, s4.w};
    int dd[4] = {d4.x, d4.y, d4.z, d4.w};
    float4 aa[4] = {a0, a1, a2, a3};
    int pos[4];
#pragma unroll
    for (int j = 0; j < 4; j++) pos[j] = atomicAdd(&cursor[dd[j]], 1);
#pragma unroll
    for (int j = 0; j < 4; j++) {
      uint4 r;
      r.x = (unsigned)ss[j] | ((unsigned)(dd[j] & 0x7FFF) << 17);
      r.y = ((unsigned)dd[j] >> 15) | ((unsigned)(base + j) << 2);
      r.z = pack2bf(aa[j].x, aa[j].y);
      r.w = pack2bf(aa[j].z, aa[j].w);
      rec[pos[j]] = r;
      src4[pos[j]] = (unsigned)ss[j];
    }
  } else {
    for (int e = base; e < E; e++) {
      int s = ei[e];
      int d = ei[E + e];
      float4 a4 = *(const float4*)(attr + (size_t)e * 4);
      int pos = atomicAdd(&cursor[d], 1);
      uint4 r;
      r.x = (unsigned)s | ((unsigned)(d & 0x7FFF) << 17);
      r.y = ((unsigned)d >> 15) | ((unsigned)e << 2);
      r.z = pack2bf(a4.x, a4.y);
      r.w = pack2bf(a4.z, a4.w);
      rec[pos] = r;
      src4[pos] = (unsigned)s;
    }
  }
}

// ---- pack weights into bf16 MFMA B-fragment layouts ----
__global__ void pack_weights(const float* __restrict__ w2_root,
                             const float* __restrict__ w2_neigh,
                             const float* __restrict__ w_e1,
                             const float* __restrict__ w_e2,
                             const float* __restrict__ b_e1,
                             u16* __restrict__ B2f, u16* __restrict__ WSDf,
                             u16* __restrict__ W2f, float* __restrict__ pbias) {
  int t = blockIdx.x * 256 + threadIdx.x;
  if (t < 32768) {  // B2f: KT=8, NT=8 over [w2_root; w2_neigh] (K=256, N=128)
    int j = t & 7, lane = (t >> 3) & 63, nt = (t >> 9) & 7, kt = t >> 12;
    int k = kt * 32 + (lane >> 4) * 8 + j;
    int n = nt * 16 + (lane & 15);
    float v = (k < 128) ? w2_root[k * 128 + n] : w2_neigh[(k - 128) * 128 + n];
    B2f[t] = f2b(v);
  } else if (t < 65536) {  // WSDf: KT=4, NT=16 over [Ws | Wd] (K=128, N=256)
    int t2 = t - 32768;
    int j = t2 & 7, lane = (t2 >> 3) & 63, nt = (t2 >> 9) & 15, kt = t2 >> 13;
    int k = kt * 32 + (lane >> 4) * 8 + j;
    int n = nt * 16 + (lane & 15);
    float v = (n < 128) ? w_e1[k * 128 + n] : w_e1[(128 + k) * 128 + (n - 128)];
    WSDf[t2] = f2b(v);
  } else if (t < 73728) {  // W2f: KT=4, NT=4 over w_e2 (K=128, N=64)
    int t2 = t - 65536;
    int j = t2 & 7, lane = (t2 >> 3) & 63, nt = (t2 >> 9) & 3, kt = t2 >> 11;
    int k = kt * 32 + (lane >> 4) * 8 + j;
    int n = nt * 16 + (lane & 15);
    W2f[t2] = f2b(w_e2[k * 64 + n]);
  } else if (t < 73984) {  // pbias
    int n = t - 73728;
    pbias[n] = (n < 128) ? 0.0f : b_e1[n - 128];
  }
}

// ---- layer-1 mean aggregation: wave/node, 8 rows x 8 lanes, 4-deep ----
__global__ __launch_bounds__(256) void agg1_kernel(
    const float* __restrict__ x, const int* __restrict__ rowptr,
    const unsigned* __restrict__ src4, float* __restrict__ mean1, int N) {
  int n = blockIdx.x * 4 + (threadIdx.x >> 6);
  if (n >= N) return;
  int lane = threadIdx.x & 63;
  int g = lane >> 3;
  int c = lane & 7;
  int beg = rowptr[n], end = rowptr[n + 1];
  float a = 0.0f;
  if (c < 6) {
    int idx[4];
#pragma unroll
    for (int j = 0; j < 4; j++) {
      int ii = beg + g + j * 8;
      idx[j] = (ii < end) ? (int)src4[ii] : -1;
    }
    float v[4];
#pragma unroll
    for (int j = 0; j < 4; j++)
      v[j] = x[(size_t)(idx[j] < 0 ? 0 : idx[j]) * 6 + c];
#pragma unroll
    for (int j = 0; j < 4; j++)
      if (idx[j] >= 0) a += v[j];
    for (int ii = beg + g + 32; ii < end; ii += 8) {
      a += x[(size_t)src4[ii] * 6 + c];
    }
  }
  a += __shfl_xor(a, 8, 64);
  a += __shfl_xor(a, 16, 64);
  a += __shfl_xor(a, 32, 64);
  if (g == 0 && c < 6)
    mean1[(size_t)n * 6 + c] = a / (float)max(end - beg, 1);
}

// ---- dense layer 1 -> h1 bf16 into cat2b cols 0..127, LDS-staged ----
__global__ __launch_bounds__(256) void dense1_kernel(
    const float* __restrict__ x, const float* __restrict__ mean1,
    const float* __restrict__ w_root, const float* __restrict__ w_neigh,
    const float* __restrict__ b, u16* __restrict__ cat2b, int N) {
  __shared__ float sxm[384];
  int t = threadIdx.x;
  int col = t & 127;
  int half = t >> 7;
  float wr[6], wn[6];
#pragma unroll
  for (int j = 0; j < 6; j++) {
    wr[j] = w_root[j * 128 + col];
    wn[j] = w_neigh[j * 128 + col];
  }
  float bb = b[col];
  for (int base = blockIdx.x * 32; base < N; base += gridDim.x * 32) {
    int cnt = min(32, N - base) * 6;
    __syncthreads();
    for (int i = t; i < 384; i += 256) {
      if (i < 192)
        sxm[i] = (i < cnt) ? x[(size_t)base * 6 + i] : 0.0f;
      else
        sxm[i] = (i - 192 < cnt) ? mean1[(size_t)base * 6 + (i - 192)] : 0.0f;
    }
    __syncthreads();
#pragma unroll
    for (int sub = 0; sub < 16; sub++) {
      int nl = sub * 2 + half;
      int n = base + nl;
      if (n < N) {
        float s = bb;
#pragma unroll
        for (int j = 0; j < 6; j++)
          s += sxm[nl * 6 + j] * wr[j] + sxm[192 + nl * 6 + j] * wn[j];
        cat2b[(size_t)n * 256 + col] = f2b(fmaxf(s, 0.0f));
      }
    }
  }
}

// ---- layer-2 mean aggregation: wave/node, 4x16 lanes, 8-deep prefetch ----
__global__ __launch_bounds__(256) void agg2_kernel(
    const u16* __restrict__ cat2b, u16* __restrict__ cat2w,
    const int* __restrict__ rowptr, const unsigned* __restrict__ src4, int N) {
  int n = blockIdx.x * 4 + (threadIdx.x >> 6);
  if (n >= N) return;
  int lane = threadIdx.x & 63;
  int g = lane >> 4;
  int c = lane & 15;
  int beg = rowptr[n], end = rowptr[n + 1];
  f32x2 acc2[4];
#pragma unroll
  for (int j = 0; j < 4; j++) acc2[j] = (f32x2){0.f, 0.f};

  const int DEPTH = 8;
  int idx[DEPTH];
#pragma unroll
  for (int j = 0; j < DEPTH; j++) {
    int ii = beg + g + j * 4;
    idx[j] = (ii < end) ? (int)src4[ii] : -1;
  }
  uint4 u[DEPTH];
#pragma unroll
  for (int j = 0; j < DEPTH; j++) {
    int s = idx[j] < 0 ? 0 : idx[j];
    u[j] = *(const uint4*)(cat2b + (size_t)s * 256 + c * 8);
  }
#pragma unroll
  for (int j = 0; j < DEPTH; j++) {
    if (idx[j] >= 0) {
      acc2[0] += unpk2(u[j].x);
      acc2[1] += unpk2(u[j].y);
      acc2[2] += unpk2(u[j].z);
      acc2[3] += unpk2(u[j].w);
    }
  }
  for (int ii = beg + g + DEPTH * 4; ii < end; ii += 4) {
    uint4 uu = *(const uint4*)(cat2b + (size_t)src4[ii] * 256 + c * 8);
    acc2[0] += unpk2(uu.x);
    acc2[1] += unpk2(uu.y);
    acc2[2] += unpk2(uu.z);
    acc2[3] += unpk2(uu.w);
  }
#pragma unroll
  for (int j = 0; j < 4; j++) {
    acc2[j].x += __shfl_xor(acc2[j].x, 16, 64);
    acc2[j].y += __shfl_xor(acc2[j].y, 16, 64);
    acc2[j].x += __shfl_xor(acc2[j].x, 32, 64);
    acc2[j].y += __shfl_xor(acc2[j].y, 32, 64);
  }
  if (g == 0) {
    float inv = 1.0f / (float)max(end - beg, 1);
    uint4 ov;
    ov.x = packrn(acc2[0] * inv);
    ov.y = packrn(acc2[1] * inv);
    ov.z = packrn(acc2[2] * inv);
    ov.w = packrn(acc2[3] * inv);
    *(uint4*)(cat2w + (size_t)n * 256 + 128 + c * 8) = ov;
  }
}

// ---- bf16 MFMA GEMM: 512 thr, 8 waves, M-tile 128 ----
template <int KT, int NT, bool RELU>
__global__ __launch_bounds__(512) void mfma_gemm(
    const u16* __restrict__ A, int lda, const u16* __restrict__ Bf,
    const float* __restrict__ bias, u16* __restrict__ C, int ldc, int M) {
  __shared__ u16 sB[KT * NT * 512];
  int tid = threadIdx.x;
  for (int i = tid; i < KT * NT * 64; i += 512)
    ((uint4*)sB)[i] = ((const uint4*)Bf)[i];
  int w = tid >> 6, l = tid & 63;
  int quad = l >> 4, col16 = l & 15;
  int rowA = blockIdx.x * 128 + w * 16 + col16;
  bool rv = rowA < M;
  const u16* ap = A + (size_t)rowA * lda + quad * 8;
  f32x4 acc[NT];
#pragma unroll
  for (int nt = 0; nt < NT; nt++) acc[nt] = (f32x4){0.f, 0.f, 0.f, 0.f};
  __syncthreads();
#pragma unroll
  for (int kt = 0; kt < KT; kt++) {
    bf16x8 av = {};
    if (rv) av = *(const bf16x8*)(ap + kt * 32);
#pragma unroll
    for (int nt = 0; nt < NT; nt++) {
      bf16x8 bv = *(const bf16x8*)(sB + ((kt * NT + nt) * 64 + l) * 8);
      acc[nt] = __builtin_amdgcn_mfma_f32_16x16x32_bf16(av, bv, acc[nt], 0, 0, 0);
    }
  }
  int rowbase = blockIdx.x * 128 + w * 16 + quad * 4;
#pragma unroll
  for (int r = 0; r < 4; r++) {
    int row = rowbase + r;
    if (row < M) {
#pragma unroll
      for (int nt = 0; nt < NT; nt++) {
        float v = acc[nt][r] + bias[nt * 16 + col16];
        if (RELU) v = fmaxf(v, 0.0f);
        C[(size_t)row * ldc + nt * 16 + col16] = f2b(v);
      }
    }
  }
}

// ---- pipelined edge MLP, packed record, single-buffer LDS ----
__global__ __launch_bounds__(256) void edge_mfma_kernel(
    const u16* __restrict__ Pcatb, const uint4* __restrict__ rec,
    const u16* __restrict__ W2f, const float* __restrict__ b_e2,
    const float* __restrict__ w_e3, const float* __restrict__ b_e3,
    const float* __restrict__ w_e1, float* __restrict__ out, int E) {
  __shared__ u16 sV[64 * 136];  // cols 0..127 = V, u16 slot 128.. = eid
  __shared__ u16 sW2[8192];

  int tid = threadIdx.x;
  int w = tid >> 6, l = tid & 63, quad = l >> 4, c16 = l & 15;
  int egrp = tid >> 4, ac16 = tid & 15;

  for (int i = tid; i < 1024; i += 256)
    ((uint4*)sW2)[i] = ((const uint4*)W2f)[i];

  f32x2 wa2[4][4];
#pragma unroll
  for (int j = 0; j < 4; j++) {
    float4 w0 = *(const float4*)(w_e1 + (256 + j) * 128 + ac16 * 8);
    float4 w1 = *(const float4*)(w_e1 + (256 + j) * 128 + ac16 * 8 + 4);
    wa2[j][0] = (f32x2){w0.x, w0.y};
    wa2[j][1] = (f32x2){w0.z, w0.w};
    wa2[j][2] = (f32x2){w1.x, w1.y};
    wa2[j][3] = (f32x2){w1.z, w1.w};
  }
  float w3v[4], be2[4];
#pragma unroll
  for (int nt = 0; nt < 4; nt++) {
    w3v[nt] = w_e3[nt * 16 + c16];
    be2[nt] = b_e2[nt * 16 + c16];
  }
  float b3 = b_e3[0];

  int tiles = (E + 63) >> 6;
  int S = gridDim.x;

  uint4 rc[4], rcn[4];
  uint4 ps[4], pd[4];
  int eidr[4];

  auto load_rc = [&](int t, uint4* dst) {
#pragma unroll
    for (int it = 0; it < 4; it++) {
      int e = min(t * 64 + it * 16 + egrp, E - 1);
      dst[it] = rec[e];
    }
  };
  auto issue_gather = [&]() {
#pragma unroll
    for (int it = 0; it < 4; it++) {
      int s = (int)(rc[it].x & NMASK);
      int d = (int)(((rc[it].x >> 17) | (rc[it].y << 15)) & NMASK);
      eidr[it] = (int)(rc[it].y >> 2);
      ps[it] = *(const uint4*)(Pcatb + (size_t)s * 256 + ac16 * 8);
      pd[it] = *(const uint4*)(Pcatb + (size_t)d * 256 + 128 + ac16 * 8);
    }
  };

  int t = blockIdx.x;
  if (t < tiles) {
    load_rc(t, rc);
    issue_gather();
    if (t + S < tiles) load_rc(t + S, rcn);
  }
  for (; t < tiles; t += S) {
    // ---- phase A (packed fp32): V = relu(Ps + Pd' + attr@Wa)
#pragma unroll
    for (int it = 0; it < 4; it++) {
      int e = it * 16 + egrp;
      uint4 psu = ps[it], pdu = pd[it];
      f32x2 a01 = unpk2(rc[it].z);
      f32x2 a23 = unpk2(rc[it].w);
      unsigned pu[4] = {psu.x, psu.y, psu.z, psu.w};
      unsigned du[4] = {pdu.x, pdu.y, pdu.z, pdu.w};
      uint4 ov;
      unsigned* op = (unsigned*)&ov;
#pragma unroll
      for (int p2 = 0; p2 < 4; p2++) {
        f32x2 f = unpk2(pu[p2]) + unpk2(du[p2]);
        f += a01.x * wa2[0][p2];
        f += a01.y * wa2[1][p2];
        f += a23.x * wa2[2][p2];
        f += a23.y * wa2[3][p2];
        f = __builtin_elementwise_max(f, (f32x2){0.f, 0.f});
        op[p2] = packrn(f);
      }
      *(uint4*)(sV + e * 136 + ac16 * 8) = ov;
      if (ac16 == 0) *(unsigned*)(sV + e * 136 + 128) = (unsigned)eidr[it];
    }
    // ---- rotate prefetch: rc <- rcn, gather t+S, load rec t+2S
    if (t + S < tiles) {
#pragma unroll
      for (int it = 0; it < 4; it++) rc[it] = rcn[it];
      issue_gather();
      if (t + 2 * S < tiles) load_rc(t + 2 * S, rcn);
    }
    __syncthreads();
    // ---- phase B: MFMA from LDS
    f32x4 acc[4];
#pragma unroll
    for (int nt = 0; nt < 4; nt++) acc[nt] = (f32x4){0.f, 0.f, 0.f, 0.f};
    const u16* vp = sV + (w * 16 + c16) * 136 + quad * 8;
#pragma unroll
    for (int kt = 0; kt < 4; kt++) {
      bf16x8 av = *(const bf16x8*)(vp + kt * 32);
#pragma unroll
      for (int nt = 0; nt < 4; nt++) {
        bf16x8 bv = *(const bf16x8*)(sW2 + ((kt * 4 + nt) * 64 + l) * 8);
        acc[nt] = __builtin_amdgcn_mfma_f32_16x16x32_bf16(av, bv, acc[nt], 0, 0, 0);
      }
    }
#pragma unroll
    for (int r = 0; r < 4; r++) {
      float p = 0.0f;
#pragma unroll
      for (int nt = 0; nt < 4; nt++)
        p += fmaxf(acc[nt][r] + be2[nt], 0.0f) * w3v[nt];
      p += __shfl_xor(p, 1, 64);
      p += __shfl_xor(p, 2, 64);
      p += __shfl_xor(p, 4, 64);
      p += __shfl_xor(p, 8, 64);
      if (c16 == 0) {
        int eloc = w * 16 + quad * 4 + r;
        if (t * 64 + eloc < E) {
          unsigned eid = *(const unsigned*)(sV + eloc * 136 + 128);
          out[eid] = p + b3;
        }
      }
    }
    __syncthreads();  // protect sV before next tile's phase A writes
  }
}

extern "C" void kernel_launch(void* const* d_in, const int* in_sizes, int n_in,
                              void* d_out, int out_size, void* d_ws,
                              size_t ws_size, hipStream_t stream) {
  const float* x        = (const float*)d_in[0];
  const int*   ei       = (const int*)d_in[1];
  const float* attr     = (const float*)d_in[2];
  const float* w1_root  = (const float*)d_in[3];
  const float* w1_neigh = (const float*)d_in[4];
  const float* b1       = (const float*)d_in[5];
  const float* w2_root  = (const float*)d_in[6];
  const float* w2_neigh = (const float*)d_in[7];
  const float* b2       = (const float*)d_in[8];
  const float* w_e1     = (const float*)d_in[9];
  const float* b_e1     = (const float*)d_in[10];
  const float* w_e2     = (const float*)d_in[11];
  const float* b_e2     = (const float*)d_in[12];
  const float* w_e3     = (const float*)d_in[13];
  const float* b_e3     = (const float*)d_in[14];
  float* out = (float*)d_out;

  int N = in_sizes[0] / 6;
  int E = in_sizes[2] / 4;
  int NBLK = (N + 255) / 256;
  int EB4 = (E + 1023) / 1024;  // blocks for 4-edge/thread kernels

  int* wsi = (int*)d_ws;
  int*      rowptr  = wsi;                         // [N+1]
  int*      cursor  = wsi + 100004;                // [N]
  int*      partial = wsi + 200004;                // [512]
  unsigned* src4    = (unsigned*)(wsi + 200516);   // [E]
  uint4*    rec     = (uint4*)(wsi + 1800520);     // [E] x 16B
  float*    mean1   = (float*)(wsi + 8200520);     // [N,6]
  u16*      cat2b   = (u16*)(wsi + 8800520);       // [N,256] bf16
  u16*      h2b     = (u16*)(wsi + 21600520);      // [N,128] bf16 (6.4M words)
  u16*      B2f     = (u16*)(wsi + 28000520);      // 32768 u16
  u16*      WSDf    = (u16*)(wsi + 28016904);      // 32768 u16
  u16*      W2f     = (u16*)(wsi + 28033288);      // 8192 u16
  float*    pbias   = (float*)(wsi + 28037384);    // 256 f32

  (void)hipMemsetAsync(cursor, 0, (size_t)N * sizeof(int), stream);

  pack_weights<<<289, 256, 0, stream>>>(w2_root, w2_neigh, w_e1, w_e2, b_e1,
                                        B2f, WSDf, W2f, pbias);

  // CSR build (by dst), 4 edges/thread for atomic ILP
  hist_kernel<<<EB4, 256, 0, stream>>>(ei, cursor, E);
  scan_block_sums<<<NBLK, 256, 0, stream>>>(cursor, partial, N);
  scan_partials<<<1, 512, 0, stream>>>(partial, rowptr, NBLK, E, N);
  scan_final<<<NBLK, 256, 0, stream>>>(partial, cursor, rowptr, N);
  scatter_rec<<<EB4, 256, 0, stream>>>(ei, attr, cursor, rec, src4, E);

  // layer 1
  agg1_kernel<<<(N + 3) / 4, 256, 0, stream>>>(x, rowptr, src4, mean1, N);
  dense1_kernel<<<1024, 256, 0, stream>>>(x, mean1, w1_root, w1_neigh, b1,
                                          cat2b, N);

  // layer 2 aggregation (8-deep pipelined bf16 gather)
  agg2_kernel<<<(N + 3) / 4, 256, 0, stream>>>(cat2b, cat2b, rowptr, src4, N);

  int gblocks = (N + 127) / 128;
  // h2 = relu([h1|mean2] @ [w2_root;w2_neigh] + b2)
  mfma_gemm<8, 8, true><<<gblocks, 512, 0, stream>>>(cat2b, 256, B2f, b2, h2b,
                                                     128, N);
  // Pcat = h2 @ [Ws|Wd] + [0|b_e1]
  mfma_gemm<4, 16, false><<<gblocks, 512, 0, stream>>>(h2b, 128, WSDf, pbias,
                                                       cat2b, 256, N);

  // pipelined fused edge MLP
  edge_mfma_kernel<<<1024, 256, 0, stream>>>(cat2b, rec, W2f, b_e2, w_e3,
                                             b_e3, w_e1, out, E);
}